// Round 3
// baseline (1332.196 us; speedup 1.0000x reference)
//
#include <hip/hip_runtime.h>
#include <hip/hip_bf16.h>

#define NTOK 4096
#define DDIM 1024
#define HDIM 4096
#define NEXP 8
#define TM 128
#define TN 128
#define BK 64
#define LDP 72   // padded LDS row (slow fallback path only)

typedef __attribute__((ext_vector_type(4))) float f32x4;
typedef __attribute__((ext_vector_type(8))) short bf16x8;
typedef __attribute__((ext_vector_type(4))) short bf16x4;

static __device__ __forceinline__ short f2bf(float f) {
  union { __hip_bfloat16 b; short s; } u;
  u.b = __float2bfloat16(f);
  return u.s;
}

// async global->LDS, 16B per lane. LDS dest is wave-uniform base + lane*16;
// global source is per-lane (gather / pre-swizzle OK).
static __device__ __forceinline__ void gl16(const void* g, void* l) {
  __builtin_amdgcn_global_load_lds((const __attribute__((address_space(1))) void*)g,
                                   (__attribute__((address_space(3))) void*)l, 16, 0, 0);
}

// ---------------- Router: one wave per token (+ x->bf16, + per-token slot record) ------------
__global__ __launch_bounds__(256) void router_kernel(
    const float* __restrict__ x, const float* __restrict__ gw,
    const float* __restrict__ rs,
    int* __restrict__ tok_id, float* __restrict__ tok_w,
    int* __restrict__ counts, short* __restrict__ xb, int* __restrict__ tok_slot)
{
  const int wv = threadIdx.x >> 6;
  const int lane = threadIdx.x & 63;
  const int tok = blockIdx.x * 4 + wv;
  const f32x4* xr = (const f32x4*)(x + (size_t)tok * DDIM);
  f32x4 xv[4];
#pragma unroll
  for (int j = 0; j < 4; ++j) xv[j] = xr[j * 64 + lane];
  if (xb) {  // fast path: bf16 copy of x for stage A's global_load_lds
#pragma unroll
    for (int j = 0; j < 4; ++j) {
      bf16x4 bv = { f2bf(xv[j][0]), f2bf(xv[j][1]), f2bf(xv[j][2]), f2bf(xv[j][3]) };
      *(bf16x4*)(xb + (size_t)tok * DDIM + (size_t)(j * 64 + lane) * 4) = bv;
    }
  }
  float lg[NEXP];
#pragma unroll
  for (int e = 0; e < NEXP; ++e) {
    const f32x4* gr = (const f32x4*)(gw + (size_t)e * DDIM);
    float s = 0.f;
#pragma unroll
    for (int j = 0; j < 4; ++j) {
      f32x4 g = gr[j * 64 + lane];
      s += g[0]*xv[j][0] + g[1]*xv[j][1] + g[2]*xv[j][2] + g[3]*xv[j][3];
    }
#pragma unroll
    for (int off = 32; off > 0; off >>= 1) s += __shfl_down(s, off, 64);
    lg[e] = s;
  }
  if (lane == 0) {
    const float scale = rs[0];
#pragma unroll
    for (int e = 0; e < NEXP; ++e) lg[e] *= scale;
    int i0 = 0;
#pragma unroll
    for (int e = 1; e < NEXP; ++e) if (lg[e] > lg[i0]) i0 = e;   // first-occurrence max
    int i1 = (i0 == 0) ? 1 : 0;
#pragma unroll
    for (int e = 0; e < NEXP; ++e) if (e != i0 && lg[e] > lg[i1]) i1 = e;
    const float v0 = lg[i0], v1 = lg[i1];
    const float w0 = 1.f / (1.f + expf(v1 - v0));   // softmax over the 2 picked logits
    const float w1v = 1.f - w0;
    int s0 = atomicAdd(&counts[i0], 1);
    tok_id[i0 * NTOK + s0] = tok;
    tok_w[i0 * NTOK + s0] = w0;
    int s1 = atomicAdd(&counts[i1], 1);
    tok_id[i1 * NTOK + s1] = tok;
    tok_w[i1 * NTOK + s1] = w1v;
    tok_slot[tok * 2 + 0] = i0 * NTOK + s0;   // (expert, slot) packed: e = >>12, s = &4095
    tok_slot[tok * 2 + 1] = i1 * NTOK + s1;
  }
}

// ---------------- Finalize (slow fallback only): padded prefix offsets ----------------
__global__ void finalize_kernel(const int* __restrict__ counts, int* __restrict__ hoff) {
  if (threadIdx.x == 0) {
    int off = 0;
    for (int e = 0; e < NEXP; ++e) { hoff[e] = off; off += ((counts[e] + TM - 1) / TM) * TM; }
  }
}

// padded prefix offset for expert e, computed in-register from counts (kills a dispatch)
static __device__ __forceinline__ int hoff_of(const int* __restrict__ counts, int e) {
  int off = 0;
#pragma unroll
  for (int i = 0; i < NEXP; ++i)
    if (i < e) off += ((counts[i] + TM - 1) / TM) * TM;
  return off;
}

// ---------------- fp32 -> bf16 streaming convert (two tensors in one launch) --------------
__global__ __launch_bounds__(256) void convert2_kernel(
    const float* __restrict__ s0, short* __restrict__ d0,
    const float* __restrict__ s1, short* __restrict__ d1, int n4)
{
  const float* src = blockIdx.z ? s1 : s0;
  short* dst = blockIdx.z ? d1 : d0;
  int i = blockIdx.x * 256 + threadIdx.x;
  const int stride = gridDim.x * 256;
  for (; i < n4; i += stride) {
    const f32x4 v = ((const f32x4*)src)[i];
    bf16x4 b = { f2bf(v[0]), f2bf(v[1]), f2bf(v[2]), f2bf(v[3]) };
    ((bf16x4*)dst)[i] = b;
  }
}

__global__ __launch_bounds__(256) void convert_kernel(
    const float* __restrict__ src, short* __restrict__ dst, int n4)
{
  int i = blockIdx.x * 256 + threadIdx.x;
  const int stride = gridDim.x * 256;
  for (; i < n4; i += stride) {
    const f32x4 v = ((const f32x4*)src)[i];
    bf16x4 b = { f2bf(v[0]), f2bf(v[1]), f2bf(v[2]), f2bf(v[3]) };
    ((bf16x4*)dst)[i] = b;
  }
}

// ---------------- FAST Stage A: h = silu(Xb@w1b^T + b1) * (Xb@w2b^T + b2) ----------------
// m97 structure + T2 XOR-swizzle; 3 blocks/CU (LDS 49.7KB x3 = 149KB < 160KB, VGPR 108 < 170).
__global__ __launch_bounds__(256, 3) void stagea_fast(
    const short* __restrict__ xb,
    const short* __restrict__ w1b, const short* __restrict__ w2b,
    const float* __restrict__ b1, const float* __restrict__ b2,
    const int* __restrict__ tok_id,
    const int* __restrict__ counts,
    short* __restrict__ h)
{
  const int e = blockIdx.z;
  const int cnt = counts[e];
  const int mt = blockIdx.y;
  if (mt * TM >= cnt) return;
  const int nt = blockIdx.x;
  const int hb = hoff_of(counts, e);

  __shared__ __align__(16) short sA[TM * BK];
  __shared__ __align__(16) short sB1[TN * BK];
  __shared__ __align__(16) short sB2[TN * BK];
  __shared__ int srow[TM];

  const int t = threadIdx.x;
  const int lane = t & 63;
  const int wv = t >> 6;

  if (t < TM) {
    int id = tok_id[e * NTOK + mt * TM + t];
    srow[t] = id < 0 ? 0 : id;   // pad rows duplicate token 0; discarded downstream
  }
  __syncthreads();

  // staging: lane covers row sub of an 8-row slab, 16B chunk c8; source chunk is
  // XOR-swizzled by row&7 (== sub) so swizzled content lands via linear LDS DMA
  const int sub = lane >> 3;
  const int c8  = lane & 7;
  const int csw = (c8 ^ sub) * 8;          // swizzled element offset within 64-elem row
  const short* wbase1 = w1b + (size_t)e * HDIM * DDIM + (size_t)(nt * TN) * DDIM;
  const short* wbase2 = w2b + (size_t)e * HDIM * DDIM + (size_t)(nt * TN) * DDIM;
  const short* ap[4]; const short* bp1[4]; const short* bp2[4];
#pragma unroll
  for (int j = 0; j < 4; ++j) {
    const int r = wv * 32 + j * 8 + sub;
    ap[j]  = xb + (size_t)srow[r] * DDIM + csw;
    bp1[j] = wbase1 + (size_t)r * DDIM + csw;
    bp2[j] = wbase2 + (size_t)r * DDIM + csw;
  }

  const int wm = (wv >> 1) * 64;
  const int wn = (wv & 1) * 64;
  const int lr = lane & 15;
  const int lq = lane >> 4;
  const int r7 = lr & 7;                    // row&7 for all this lane's fragment rows
  const int sw0 = ((lq ^ r7) << 3);         // swizzled chunk for ks=0
  const int sw1 = (((4 + lq) ^ r7) << 3);   // swizzled chunk for ks=32

  f32x4 acc1[4][4] = {};
  f32x4 acc2[4][4] = {};

  for (int k0 = 0; k0 < DDIM; k0 += BK) {
#pragma unroll
    for (int j = 0; j < 4; ++j) {
      gl16(ap[j] + k0,  sA  + (wv * 4 + j) * 512);
      gl16(bp1[j] + k0, sB1 + (wv * 4 + j) * 512);
      gl16(bp2[j] + k0, sB2 + (wv * 4 + j) * 512);
    }
    __syncthreads();   // compiler drains vmcnt before barrier -> LDS tile ready
#pragma unroll
    for (int ks = 0; ks < 2; ++ks) {
      const int sw = ks ? sw1 : sw0;
      bf16x8 af[4], ba[4], bb[4];
#pragma unroll
      for (int mi = 0; mi < 4; ++mi)
        af[mi] = *(const bf16x8*)(sA + (wm + mi * 16 + lr) * BK + sw);
#pragma unroll
      for (int ni = 0; ni < 4; ++ni) {
        ba[ni] = *(const bf16x8*)(sB1 + (wn + ni * 16 + lr) * BK + sw);
        bb[ni] = *(const bf16x8*)(sB2 + (wn + ni * 16 + lr) * BK + sw);
      }
#pragma unroll
      for (int mi = 0; mi < 4; ++mi)
#pragma unroll
        for (int ni = 0; ni < 4; ++ni) {
          acc1[mi][ni] = __builtin_amdgcn_mfma_f32_16x16x32_bf16(af[mi], ba[ni], acc1[mi][ni], 0, 0, 0);
          acc2[mi][ni] = __builtin_amdgcn_mfma_f32_16x16x32_bf16(af[mi], bb[ni], acc2[mi][ni], 0, 0, 0);
        }
    }
    __syncthreads();   // protect LDS from next iteration's global_load_lds
  }

  const int hbase = hb + mt * TM;
#pragma unroll
  for (int ni = 0; ni < 4; ++ni) {
    const int col = nt * TN + wn + ni * 16 + lr;
    const float bb1 = b1[e * HDIM + col];
    const float bb2 = b2[e * HDIM + col];
#pragma unroll
    for (int mi = 0; mi < 4; ++mi) {
#pragma unroll
      for (int r = 0; r < 4; ++r) {
        const int row = wm + mi * 16 + lq * 4 + r;
        const float z1 = acc1[mi][ni][r] + bb1;
        const float z2 = acc2[mi][ni][r] + bb2;
        const float hv = (z1 / (1.f + expf(-z1))) * z2;
        h[(size_t)(hbase + row) * HDIM + col] = f2bf(hv);
      }
    }
  }
}

// ---------------- FAST Stage B: pout[slot] = wgt * (h @ w3b^T + b3)  (atomic-free) --------
// 4 blocks/CU (LDS 32KB x4 = 128KB < 160KB, VGPR ~56 < 128).
__global__ __launch_bounds__(256, 4) void stageb_fast(
    const short* __restrict__ hm, const short* __restrict__ w3b,
    const float* __restrict__ b3, const float* __restrict__ tok_w,
    const int* __restrict__ counts,
    float* __restrict__ pout)
{
  const int e = blockIdx.z;
  const int cnt = counts[e];
  const int mt = blockIdx.y;
  if (mt * TM >= cnt) return;
  const int nt = blockIdx.x;
  const int hb = hoff_of(counts, e);

  __shared__ __align__(16) short sA[TM * BK];
  __shared__ __align__(16) short sB[TN * BK];

  const int t = threadIdx.x;
  const int lane = t & 63;
  const int wv = t >> 6;
  const int sub = lane >> 3;
  const int c8  = lane & 7;
  const int csw = (c8 ^ sub) * 8;

  const short* hrow = hm + (size_t)(hb + mt * TM) * HDIM;
  const short* wbase = w3b + (size_t)e * DDIM * HDIM + (size_t)(nt * TN) * HDIM;
  const short* ap[4]; const short* bp[4];
#pragma unroll
  for (int j = 0; j < 4; ++j) {
    const int r = wv * 32 + j * 8 + sub;
    ap[j] = hrow + (size_t)r * HDIM + csw;
    bp[j] = wbase + (size_t)r * HDIM + csw;
  }

  const int wm = (wv >> 1) * 64;
  const int wn = (wv & 1) * 64;
  const int lr = lane & 15;
  const int lq = lane >> 4;
  const int r7 = lr & 7;
  const int sw0 = ((lq ^ r7) << 3);
  const int sw1 = (((4 + lq) ^ r7) << 3);

  f32x4 acc[4][4] = {};

  for (int k0 = 0; k0 < HDIM; k0 += BK) {
#pragma unroll
    for (int j = 0; j < 4; ++j) {
      gl16(ap[j] + k0, sA + (wv * 4 + j) * 512);
      gl16(bp[j] + k0, sB + (wv * 4 + j) * 512);
    }
    __syncthreads();
#pragma unroll
    for (int ks = 0; ks < 2; ++ks) {
      const int sw = ks ? sw1 : sw0;
      bf16x8 af[4], bfr[4];
#pragma unroll
      for (int mi = 0; mi < 4; ++mi)
        af[mi] = *(const bf16x8*)(sA + (wm + mi * 16 + lr) * BK + sw);
#pragma unroll
      for (int ni = 0; ni < 4; ++ni)
        bfr[ni] = *(const bf16x8*)(sB + (wn + ni * 16 + lr) * BK + sw);
#pragma unroll
      for (int mi = 0; mi < 4; ++mi)
#pragma unroll
        for (int ni = 0; ni < 4; ++ni)
          acc[mi][ni] = __builtin_amdgcn_mfma_f32_16x16x32_bf16(af[mi], bfr[ni], acc[mi][ni], 0, 0, 0);
    }
    __syncthreads();
  }

  // epilogue: weighted+biased partial to compact pout; pad rows write garbage that the
  // gather never reads (slot index always < cnt)
  float* prow = pout + (size_t)(hb + mt * TM) * DDIM;
#pragma unroll
  for (int ni = 0; ni < 4; ++ni) {
    const int col = nt * TN + wn + ni * 16 + lr;
    const float bb3 = b3[e * DDIM + col];
#pragma unroll
    for (int mi = 0; mi < 4; ++mi) {
#pragma unroll
      for (int r = 0; r < 4; ++r) {
        const int row = wm + mi * 16 + lq * 4 + r;
        const float wgt = tok_w[e * NTOK + mt * TM + row];
        prow[(size_t)row * DDIM + col] = wgt * (acc[mi][ni][r] + bb3);
      }
    }
  }
}

// ---------------- Gather: y[tok] = pout[slot0] + pout[slot1] ----------------
__global__ __launch_bounds__(256) void gather_kernel(
    const float* __restrict__ pout, const int* __restrict__ tok_slot,
    const int* __restrict__ counts, float* __restrict__ y)
{
  const int tok = blockIdx.x;
  const int c = threadIdx.x;
  int off[NEXP];
  {
    int o = 0;
#pragma unroll
    for (int i = 0; i < NEXP; ++i) { off[i] = o; o += ((counts[i] + TM - 1) / TM) * TM; }
  }
  const int es0 = tok_slot[tok * 2 + 0];
  const int es1 = tok_slot[tok * 2 + 1];
  const size_t p0 = (size_t)(off[es0 >> 12] + (es0 & 4095));
  const size_t p1 = (size_t)(off[es1 >> 12] + (es1 & 4095));
  const f32x4 a = ((const f32x4*)pout)[p0 * 256 + c];
  const f32x4 b = ((const f32x4*)pout)[p1 * 256 + c];
  ((f32x4*)y)[(size_t)tok * 256 + c] = a + b;
}

// ================= SLOW fallback path (previous verified kernels) =================
__global__ __launch_bounds__(256, 2) void stagea_kernel(
    const float* __restrict__ x,
    const float* __restrict__ w1, const float* __restrict__ b1,
    const float* __restrict__ w2, const float* __restrict__ b2,
    const int* __restrict__ tok_id,
    const int* __restrict__ counts, const int* __restrict__ hoff,
    short* __restrict__ h)
{
  const int e = blockIdx.z;
  const int cnt = counts[e];
  const int mt = blockIdx.y;
  if (mt * TM >= cnt) return;
  const int nt = blockIdx.x;

  __shared__ __align__(16) short sA[TM * LDP];
  __shared__ __align__(16) short sB1[TN * LDP];
  __shared__ __align__(16) short sB2[TN * LDP];
  __shared__ int srow[TM];

  const int t = threadIdx.x;
  if (t < TM) {
    int id = tok_id[e * NTOK + mt * TM + t];
    srow[t] = id < 0 ? 0 : id;
  }

  const float* wa = w1 + (size_t)e * HDIM * DDIM + (size_t)(nt * TN) * DDIM;
  const float* wb = w2 + (size_t)e * HDIM * DDIM + (size_t)(nt * TN) * DDIM;

  const int lane = t & 63;
  const int wv = t >> 6;
  const int wm = (wv >> 1) * 64;
  const int wn = (wv & 1) * 64;
  const int lr = lane & 15;
  const int lq = lane >> 4;

  f32x4 acc1[4][4] = {};
  f32x4 acc2[4][4] = {};

  const int r0 = t >> 4;
  const int c4 = t & 15;

  for (int k0 = 0; k0 < DDIM; k0 += BK) {
    __syncthreads();
#pragma unroll
    for (int j = 0; j < 8; ++j) {
      const int r = r0 + j * 16;
      const f32x4 v = *(const f32x4*)(x + (size_t)srow[r] * DDIM + k0 + c4 * 4);
      bf16x4 bv = { f2bf(v[0]), f2bf(v[1]), f2bf(v[2]), f2bf(v[3]) };
      *(bf16x4*)(sA + r * LDP + c4 * 4) = bv;
    }
#pragma unroll
    for (int j = 0; j < 8; ++j) {
      const int r = r0 + j * 16;
      const f32x4 v1 = *(const f32x4*)(wa + (size_t)r * DDIM + k0 + c4 * 4);
      bf16x4 b1v = { f2bf(v1[0]), f2bf(v1[1]), f2bf(v1[2]), f2bf(v1[3]) };
      *(bf16x4*)(sB1 + r * LDP + c4 * 4) = b1v;
      const f32x4 v2 = *(const f32x4*)(wb + (size_t)r * DDIM + k0 + c4 * 4);
      bf16x4 b2v = { f2bf(v2[0]), f2bf(v2[1]), f2bf(v2[2]), f2bf(v2[3]) };
      *(bf16x4*)(sB2 + r * LDP + c4 * 4) = b2v;
    }
    __syncthreads();
#pragma unroll
    for (int ks = 0; ks < BK; ks += 32) {
      bf16x8 af[4], bfa[4], bfb[4];
#pragma unroll
      for (int mi = 0; mi < 4; ++mi)
        af[mi] = *(const bf16x8*)(sA + (wm + mi * 16 + lr) * LDP + ks + lq * 8);
#pragma unroll
      for (int ni = 0; ni < 4; ++ni) {
        bfa[ni] = *(const bf16x8*)(sB1 + (wn + ni * 16 + lr) * LDP + ks + lq * 8);
        bfb[ni] = *(const bf16x8*)(sB2 + (wn + ni * 16 + lr) * LDP + ks + lq * 8);
      }
#pragma unroll
      for (int mi = 0; mi < 4; ++mi)
#pragma unroll
        for (int ni = 0; ni < 4; ++ni) {
          acc1[mi][ni] = __builtin_amdgcn_mfma_f32_16x16x32_bf16(af[mi], bfa[ni], acc1[mi][ni], 0, 0, 0);
          acc2[mi][ni] = __builtin_amdgcn_mfma_f32_16x16x32_bf16(af[mi], bfb[ni], acc2[mi][ni], 0, 0, 0);
        }
    }
  }

  const int hbase = hoff[e] + mt * TM;
#pragma unroll
  for (int ni = 0; ni < 4; ++ni) {
    const int col = nt * TN + wn + ni * 16 + lr;
    const float bb1 = b1[e * HDIM + col];
    const float bb2 = b2[e * HDIM + col];
#pragma unroll
    for (int mi = 0; mi < 4; ++mi) {
#pragma unroll
      for (int r = 0; r < 4; ++r) {
        const int row = wm + mi * 16 + lq * 4 + r;
        const float z1 = acc1[mi][ni][r] + bb1;
        const float z2 = acc2[mi][ni][r] + bb2;
        const float hv = (z1 / (1.f + expf(-z1))) * z2;
        h[(size_t)(hbase + row) * HDIM + col] = f2bf(hv);
      }
    }
  }
}

__global__ __launch_bounds__(256, 2) void stageb_kernel(
    const short* __restrict__ h,
    const float* __restrict__ w3, const float* __restrict__ b3,
    const int* __restrict__ tok_id, const float* __restrict__ tok_w,
    const int* __restrict__ counts, const int* __restrict__ hoff,
    float* __restrict__ y)
{
  const int e = blockIdx.z;
  const int cnt = counts[e];
  const int mt = blockIdx.y;
  if (mt * TM >= cnt) return;
  const int nt = blockIdx.x;

  __shared__ __align__(16) short sA[TM * LDP];
  __shared__ __align__(16) short sB[TN * LDP];

  const int t = threadIdx.x;
  const int lane = t & 63;
  const int wv = t >> 6;
  const int wm = (wv >> 1) * 64;
  const int wn = (wv & 1) * 64;
  const int lr = lane & 15;
  const int lq = lane >> 4;

  const short* hrow = h + (size_t)(hoff[e] + mt * TM) * HDIM;
  const float* wc = w3 + (size_t)e * DDIM * HDIM + (size_t)(nt * TN) * HDIM;

  f32x4 acc[4][4] = {};

  const int rA = t >> 3;
  const int c8 = t & 7;
  const int rB = t >> 4;
  const int c4 = t & 15;

  for (int k0 = 0; k0 < HDIM; k0 += BK) {
    __syncthreads();
#pragma unroll
    for (int j = 0; j < 4; ++j) {
      const int r = rA + j * 32;
      bf16x8 v = *(const bf16x8*)(hrow + (size_t)r * HDIM + k0 + c8 * 8);
      *(bf16x8*)(sA + r * LDP + c8 * 8) = v;
    }
#pragma unroll
    for (int j = 0; j < 8; ++j) {
      const int r = rB + j * 16;
      const f32x4 v = *(const f32x4*)(wc + (size_t)r * HDIM + k0 + c4 * 4);
      bf16x4 bv = { f2bf(v[0]), f2bf(v[1]), f2bf(v[2]), f2bf(v[3]) };
      *(bf16x4*)(sB + r * LDP + c4 * 4) = bv;
    }
    __syncthreads();
#pragma unroll
    for (int ks = 0; ks < BK; ks += 32) {
      bf16x8 af[4], bfr[4];
#pragma unroll
      for (int mi = 0; mi < 4; ++mi)
        af[mi] = *(const bf16x8*)(sA + (wm + mi * 16 + lr) * LDP + ks + lq * 8);
#pragma unroll
      for (int ni = 0; ni < 4; ++ni)
        bfr[ni] = *(const bf16x8*)(sB + (wn + ni * 16 + lr) * LDP + ks + lq * 8);
#pragma unroll
      for (int mi = 0; mi < 4; ++mi)
#pragma unroll
        for (int ni = 0; ni < 4; ++ni)
          acc[mi][ni] = __builtin_amdgcn_mfma_f32_16x16x32_bf16(af[mi], bfr[ni], acc[mi][ni], 0, 0, 0);
    }
  }

#pragma unroll
  for (int ni = 0; ni < 4; ++ni) {
    const int col = nt * TN + wn + ni * 16 + lr;
    const float bb3 = b3[e * DDIM + col];
#pragma unroll
    for (int mi = 0; mi < 4; ++mi) {
#pragma unroll
      for (int r = 0; r < 4; ++r) {
        const int row = mt * TM + wm + mi * 16 + lq * 4 + r;
        const int tok = tok_id[e * NTOK + row];
        if (tok >= 0) {
          const float wgt = tok_w[e * NTOK + row];
          atomicAdd(&y[(size_t)tok * DDIM + col], wgt * (acc[mi][ni][r] + bb3));
        }
      }
    }
  }
}

extern "C" void kernel_launch(void* const* d_in, const int* in_sizes, int n_in,
                              void* d_out, int out_size, void* d_ws, size_t ws_size,
                              hipStream_t stream) {
  const float* x  = (const float*)d_in[0];
  const float* gw = (const float*)d_in[1];
  const float* rs = (const float*)d_in[2];
  const float* w1 = (const float*)d_in[3];
  const float* b1 = (const float*)d_in[4];
  const float* w2 = (const float*)d_in[5];
  const float* b2 = (const float*)d_in[6];
  const float* w3 = (const float*)d_in[7];
  const float* b3 = (const float*)d_in[8];
  // d_in[9] = top_k (fixed 2)

  char* ws = (char*)d_ws;
  int*   tok_id   = (int*)ws;                 // E*N ints      = 131072 B
  float* tok_w    = (float*)(ws + 131072);    // E*N floats    = 131072 B
  int*   counts   = (int*)(ws + 262144);      // 8 ints
  int*   hoff     = (int*)(ws + 262176);      // 8 ints (slow path only)
  int*   tok_slot = (int*)(ws + 262208);      // N*2 ints      = 32768 B  (ends 294976)

  // fast path: xb (8.39 MB) | h (75.5 MB) | w1b (67.1 MB) | w2b (67.1 MB)
  // stage B reuses w1b for w3b and w2b for pout (37.75 MB fp32 compact partials)
  const size_t OFF_XB = 295168;
  const size_t OFF_H  = OFF_XB + 8388608ull;           // 4096*1024*2
  const size_t OFF_WB = OFF_H  + 75497472ull;          // 9216*4096*2
  const size_t FAST_REQ = OFF_WB + 134217728ull;       // = 218,398,976 B
  const bool fast = ws_size >= FAST_REQ;

  hipMemsetAsync(counts, 0, 32, stream);
  hipMemsetAsync(tok_id, 0xFF, 131072, stream);   // pad token id = -1

  if (fast) {
    short* xb   = (short*)(ws + OFF_XB);
    short* h    = (short*)(ws + OFF_H);
    short* w1b  = (short*)(ws + OFF_WB);
    short* w2b  = w1b + 33554432;                 // 8*4096*1024 bf16
    float* pout = (float*)(ws + OFF_WB + 67108864ull);  // aliases w2b slot (dead after A)
    const int W4 = 8388608;                       // f32x4 count per weight tensor

    router_kernel<<<dim3(NTOK / 4), dim3(256), 0, stream>>>(x, gw, rs, tok_id, tok_w, counts, xb, tok_slot);
    convert2_kernel<<<dim3(2048, 1, 2), dim3(256), 0, stream>>>(w1, w1b, w2, w2b, W4);
    stagea_fast<<<dim3(HDIM / TN, NTOK / TM, NEXP), dim3(256), 0, stream>>>(
        xb, w1b, w2b, b1, b2, tok_id, counts, h);
    // w3 -> bf16 reuses the w1b slot (stage A done with it; stream-ordered)
    convert_kernel<<<dim3(2048), dim3(256), 0, stream>>>(w3, w1b, W4);
    stageb_fast<<<dim3(DDIM / TN, NTOK / TM, NEXP), dim3(256), 0, stream>>>(
        h, w1b, b3, tok_w, counts, pout);
    gather_kernel<<<dim3(NTOK), dim3(256), 0, stream>>>(pout, tok_slot, counts, (float*)d_out);
  } else {
    short* h = (short*)(ws + OFF_XB);
    hipMemsetAsync(d_out, 0, (size_t)out_size * sizeof(float), stream);
    router_kernel<<<dim3(NTOK / 4), dim3(256), 0, stream>>>(x, gw, rs, tok_id, tok_w, counts, (short*)nullptr, tok_slot);
    finalize_kernel<<<dim3(1), dim3(64), 0, stream>>>(counts, hoff);
    stagea_kernel<<<dim3(HDIM / TN, NTOK / TM, NEXP), dim3(256), 0, stream>>>(
        x, w1, b1, w2, b2, tok_id, counts, hoff, h);
    stageb_kernel<<<dim3(DDIM / TN, NTOK / TM, NEXP), dim3(256), 0, stream>>>(
        h, w3, b3, tok_id, tok_w, counts, hoff, (float*)d_out);
  }
}

// Round 4
// 819.872 us; speedup vs baseline: 1.6249x; 1.6249x over previous
//
#include <hip/hip_runtime.h>
#include <hip/hip_bf16.h>

#define NTOK 4096
#define DDIM 1024
#define HDIM 4096
#define NEXP 8
#define TM 128
#define TN 128
#define BK 64
#define LDP 72   // padded LDS row (slow fallback path only)

typedef __attribute__((ext_vector_type(4))) float f32x4;
typedef __attribute__((ext_vector_type(8))) short bf16x8;
typedef __attribute__((ext_vector_type(4))) short bf16x4;

static __device__ __forceinline__ short f2bf(float f) {
  union { __hip_bfloat16 b; short s; } u;
  u.b = __float2bfloat16(f);
  return u.s;
}

// async global->LDS, 16B per lane. LDS dest is wave-uniform base + lane*16;
// global source is per-lane (gather / pre-swizzle OK).
static __device__ __forceinline__ void gl16(const void* g, void* l) {
  __builtin_amdgcn_global_load_lds((const __attribute__((address_space(1))) void*)g,
                                   (__attribute__((address_space(3))) void*)l, 16, 0, 0);
}

// ---------------- Router: one wave per token (+ x->bf16, + per-token slot record) ------------
__global__ __launch_bounds__(256) void router_kernel(
    const float* __restrict__ x, const float* __restrict__ gw,
    const float* __restrict__ rs,
    int* __restrict__ tok_id, float* __restrict__ tok_w,
    int* __restrict__ counts, short* __restrict__ xb, int* __restrict__ tok_slot)
{
  const int wv = threadIdx.x >> 6;
  const int lane = threadIdx.x & 63;
  const int tok = blockIdx.x * 4 + wv;
  const f32x4* xr = (const f32x4*)(x + (size_t)tok * DDIM);
  f32x4 xv[4];
#pragma unroll
  for (int j = 0; j < 4; ++j) xv[j] = xr[j * 64 + lane];
  if (xb) {  // fast path: bf16 copy of x for stage A's global_load_lds
#pragma unroll
    for (int j = 0; j < 4; ++j) {
      bf16x4 bv = { f2bf(xv[j][0]), f2bf(xv[j][1]), f2bf(xv[j][2]), f2bf(xv[j][3]) };
      *(bf16x4*)(xb + (size_t)tok * DDIM + (size_t)(j * 64 + lane) * 4) = bv;
    }
  }
  float lg[NEXP];
#pragma unroll
  for (int e = 0; e < NEXP; ++e) {
    const f32x4* gr = (const f32x4*)(gw + (size_t)e * DDIM);
    float s = 0.f;
#pragma unroll
    for (int j = 0; j < 4; ++j) {
      f32x4 g = gr[j * 64 + lane];
      s += g[0]*xv[j][0] + g[1]*xv[j][1] + g[2]*xv[j][2] + g[3]*xv[j][3];
    }
#pragma unroll
    for (int off = 32; off > 0; off >>= 1) s += __shfl_down(s, off, 64);
    lg[e] = s;
  }
  if (lane == 0) {
    const float scale = rs[0];
#pragma unroll
    for (int e = 0; e < NEXP; ++e) lg[e] *= scale;
    int i0 = 0;
#pragma unroll
    for (int e = 1; e < NEXP; ++e) if (lg[e] > lg[i0]) i0 = e;   // first-occurrence max
    int i1 = (i0 == 0) ? 1 : 0;
#pragma unroll
    for (int e = 0; e < NEXP; ++e) if (e != i0 && lg[e] > lg[i1]) i1 = e;
    const float v0 = lg[i0], v1 = lg[i1];
    const float w0 = 1.f / (1.f + expf(v1 - v0));   // softmax over the 2 picked logits
    const float w1v = 1.f - w0;
    int s0 = atomicAdd(&counts[i0], 1);
    tok_id[i0 * NTOK + s0] = tok;
    tok_w[i0 * NTOK + s0] = w0;
    int s1 = atomicAdd(&counts[i1], 1);
    tok_id[i1 * NTOK + s1] = tok;
    tok_w[i1 * NTOK + s1] = w1v;
    tok_slot[tok * 2 + 0] = i0 * NTOK + s0;   // (expert, slot) packed: e = >>12, s = &4095
    tok_slot[tok * 2 + 1] = i1 * NTOK + s1;
  }
}

// ---------------- Finalize (slow fallback only): padded prefix offsets ----------------
__global__ void finalize_kernel(const int* __restrict__ counts, int* __restrict__ hoff) {
  if (threadIdx.x == 0) {
    int off = 0;
    for (int e = 0; e < NEXP; ++e) { hoff[e] = off; off += ((counts[e] + TM - 1) / TM) * TM; }
  }
}

// padded prefix offset for expert e, computed in-register from counts (kills a dispatch)
static __device__ __forceinline__ int hoff_of(const int* __restrict__ counts, int e) {
  int off = 0;
#pragma unroll
  for (int i = 0; i < NEXP; ++i)
    if (i < e) off += ((counts[i] + TM - 1) / TM) * TM;
  return off;
}

// ---------------- fp32 -> bf16 streaming convert (two tensors in one launch) --------------
__global__ __launch_bounds__(256) void convert2_kernel(
    const float* __restrict__ s0, short* __restrict__ d0,
    const float* __restrict__ s1, short* __restrict__ d1, int n4)
{
  const float* src = blockIdx.z ? s1 : s0;
  short* dst = blockIdx.z ? d1 : d0;
  int i = blockIdx.x * 256 + threadIdx.x;
  const int stride = gridDim.x * 256;
  for (; i < n4; i += stride) {
    const f32x4 v = ((const f32x4*)src)[i];
    bf16x4 b = { f2bf(v[0]), f2bf(v[1]), f2bf(v[2]), f2bf(v[3]) };
    ((bf16x4*)dst)[i] = b;
  }
}

__global__ __launch_bounds__(256) void convert_kernel(
    const float* __restrict__ src, short* __restrict__ dst, int n4)
{
  int i = blockIdx.x * 256 + threadIdx.x;
  const int stride = gridDim.x * 256;
  for (; i < n4; i += stride) {
    const f32x4 v = ((const f32x4*)src)[i];
    bf16x4 b = { f2bf(v[0]), f2bf(v[1]), f2bf(v[2]), f2bf(v[3]) };
    ((bf16x4*)dst)[i] = b;
  }
}

// ---------------- FAST Stage A: h = silu(Xb@w1b^T + b1) * (Xb@w2b^T + b2) ----------------
// m97 structure + T2 XOR-swizzle. NOTE register floor: ~108 VGPR + 128 acc regs ~= 236/wave
// -> (256,2) is the max occupancy without spilling (round-3 post-mortem: (256,3) spilled
// the accumulators, WRITE_SIZE 70MB -> 1.4GB, 3x slower). Do not raise.
__global__ __launch_bounds__(256, 2) void stagea_fast(
    const short* __restrict__ xb,
    const short* __restrict__ w1b, const short* __restrict__ w2b,
    const float* __restrict__ b1, const float* __restrict__ b2,
    const int* __restrict__ tok_id,
    const int* __restrict__ counts,
    short* __restrict__ h)
{
  const int e = blockIdx.z;
  const int cnt = counts[e];
  const int mt = blockIdx.y;
  if (mt * TM >= cnt) return;
  const int nt = blockIdx.x;
  const int hb = hoff_of(counts, e);

  __shared__ __align__(16) short sA[TM * BK];
  __shared__ __align__(16) short sB1[TN * BK];
  __shared__ __align__(16) short sB2[TN * BK];
  __shared__ int srow[TM];

  const int t = threadIdx.x;
  const int lane = t & 63;
  const int wv = t >> 6;

  if (t < TM) {
    int id = tok_id[e * NTOK + mt * TM + t];
    srow[t] = id < 0 ? 0 : id;   // pad rows duplicate token 0; discarded downstream
  }
  __syncthreads();

  // staging: lane covers row sub of an 8-row slab, 16B chunk c8; source chunk is
  // XOR-swizzled by row&7 (== sub) so swizzled content lands via linear LDS DMA
  const int sub = lane >> 3;
  const int c8  = lane & 7;
  const int csw = (c8 ^ sub) * 8;          // swizzled element offset within 64-elem row
  const short* wbase1 = w1b + (size_t)e * HDIM * DDIM + (size_t)(nt * TN) * DDIM;
  const short* wbase2 = w2b + (size_t)e * HDIM * DDIM + (size_t)(nt * TN) * DDIM;
  const short* ap[4]; const short* bp1[4]; const short* bp2[4];
#pragma unroll
  for (int j = 0; j < 4; ++j) {
    const int r = wv * 32 + j * 8 + sub;
    ap[j]  = xb + (size_t)srow[r] * DDIM + csw;
    bp1[j] = wbase1 + (size_t)r * DDIM + csw;
    bp2[j] = wbase2 + (size_t)r * DDIM + csw;
  }

  const int wm = (wv >> 1) * 64;
  const int wn = (wv & 1) * 64;
  const int lr = lane & 15;
  const int lq = lane >> 4;
  const int r7 = lr & 7;                    // row&7 for all this lane's fragment rows
  const int sw0 = ((lq ^ r7) << 3);         // swizzled chunk for ks=0
  const int sw1 = (((4 + lq) ^ r7) << 3);   // swizzled chunk for ks=32

  f32x4 acc1[4][4] = {};
  f32x4 acc2[4][4] = {};

  for (int k0 = 0; k0 < DDIM; k0 += BK) {
#pragma unroll
    for (int j = 0; j < 4; ++j) {
      gl16(ap[j] + k0,  sA  + (wv * 4 + j) * 512);
      gl16(bp1[j] + k0, sB1 + (wv * 4 + j) * 512);
      gl16(bp2[j] + k0, sB2 + (wv * 4 + j) * 512);
    }
    __syncthreads();   // compiler drains vmcnt before barrier -> LDS tile ready
#pragma unroll
    for (int ks = 0; ks < 2; ++ks) {
      const int sw = ks ? sw1 : sw0;
      bf16x8 af[4], ba[4], bb[4];
#pragma unroll
      for (int mi = 0; mi < 4; ++mi)
        af[mi] = *(const bf16x8*)(sA + (wm + mi * 16 + lr) * BK + sw);
#pragma unroll
      for (int ni = 0; ni < 4; ++ni) {
        ba[ni] = *(const bf16x8*)(sB1 + (wn + ni * 16 + lr) * BK + sw);
        bb[ni] = *(const bf16x8*)(sB2 + (wn + ni * 16 + lr) * BK + sw);
      }
#pragma unroll
      for (int mi = 0; mi < 4; ++mi)
#pragma unroll
        for (int ni = 0; ni < 4; ++ni) {
          acc1[mi][ni] = __builtin_amdgcn_mfma_f32_16x16x32_bf16(af[mi], ba[ni], acc1[mi][ni], 0, 0, 0);
          acc2[mi][ni] = __builtin_amdgcn_mfma_f32_16x16x32_bf16(af[mi], bb[ni], acc2[mi][ni], 0, 0, 0);
        }
    }
    __syncthreads();   // protect LDS from next iteration's global_load_lds
  }

  const int hbase = hb + mt * TM;
#pragma unroll
  for (int ni = 0; ni < 4; ++ni) {
    const int col = nt * TN + wn + ni * 16 + lr;
    const float bb1 = b1[e * HDIM + col];
    const float bb2 = b2[e * HDIM + col];
#pragma unroll
    for (int mi = 0; mi < 4; ++mi) {
#pragma unroll
      for (int r = 0; r < 4; ++r) {
        const int row = wm + mi * 16 + lq * 4 + r;
        const float z1 = acc1[mi][ni][r] + bb1;
        const float z2 = acc2[mi][ni][r] + bb2;
        const float hv = (z1 / (1.f + expf(-z1))) * z2;
        h[(size_t)(hbase + row) * HDIM + col] = f2bf(hv);
      }
    }
  }
}

// ---------------- FAST Stage B: pout[slot] = wgt * (h @ w3b^T + b3)  (atomic-free) --------
// Register floor ~56 VGPR + 64 acc = 120/wave -> 3 waves/EU cap (~170) fits with margin.
__global__ __launch_bounds__(256, 3) void stageb_fast(
    const short* __restrict__ hm, const short* __restrict__ w3b,
    const float* __restrict__ b3, const float* __restrict__ tok_w,
    const int* __restrict__ counts,
    float* __restrict__ pout)
{
  const int e = blockIdx.z;
  const int cnt = counts[e];
  const int mt = blockIdx.y;
  if (mt * TM >= cnt) return;
  const int nt = blockIdx.x;
  const int hb = hoff_of(counts, e);

  __shared__ __align__(16) short sA[TM * BK];
  __shared__ __align__(16) short sB[TN * BK];

  const int t = threadIdx.x;
  const int lane = t & 63;
  const int wv = t >> 6;
  const int sub = lane >> 3;
  const int c8  = lane & 7;
  const int csw = (c8 ^ sub) * 8;

  const short* hrow = hm + (size_t)(hb + mt * TM) * HDIM;
  const short* wbase = w3b + (size_t)e * DDIM * HDIM + (size_t)(nt * TN) * HDIM;
  const short* ap[4]; const short* bp[4];
#pragma unroll
  for (int j = 0; j < 4; ++j) {
    const int r = wv * 32 + j * 8 + sub;
    ap[j] = hrow + (size_t)r * HDIM + csw;
    bp[j] = wbase + (size_t)r * HDIM + csw;
  }

  const int wm = (wv >> 1) * 64;
  const int wn = (wv & 1) * 64;
  const int lr = lane & 15;
  const int lq = lane >> 4;
  const int r7 = lr & 7;
  const int sw0 = ((lq ^ r7) << 3);
  const int sw1 = (((4 + lq) ^ r7) << 3);

  f32x4 acc[4][4] = {};

  for (int k0 = 0; k0 < HDIM; k0 += BK) {
#pragma unroll
    for (int j = 0; j < 4; ++j) {
      gl16(ap[j] + k0, sA + (wv * 4 + j) * 512);
      gl16(bp[j] + k0, sB + (wv * 4 + j) * 512);
    }
    __syncthreads();
#pragma unroll
    for (int ks = 0; ks < 2; ++ks) {
      const int sw = ks ? sw1 : sw0;
      bf16x8 af[4], bfr[4];
#pragma unroll
      for (int mi = 0; mi < 4; ++mi)
        af[mi] = *(const bf16x8*)(sA + (wm + mi * 16 + lr) * BK + sw);
#pragma unroll
      for (int ni = 0; ni < 4; ++ni)
        bfr[ni] = *(const bf16x8*)(sB + (wn + ni * 16 + lr) * BK + sw);
#pragma unroll
      for (int mi = 0; mi < 4; ++mi)
#pragma unroll
        for (int ni = 0; ni < 4; ++ni)
          acc[mi][ni] = __builtin_amdgcn_mfma_f32_16x16x32_bf16(af[mi], bfr[ni], acc[mi][ni], 0, 0, 0);
    }
    __syncthreads();
  }

  // epilogue: weighted+biased partial to compact pout; pad rows write garbage that the
  // gather never reads (slot index always < cnt)
  float* prow = pout + (size_t)(hb + mt * TM) * DDIM;
#pragma unroll
  for (int ni = 0; ni < 4; ++ni) {
    const int col = nt * TN + wn + ni * 16 + lr;
    const float bb3 = b3[e * DDIM + col];
#pragma unroll
    for (int mi = 0; mi < 4; ++mi) {
#pragma unroll
      for (int r = 0; r < 4; ++r) {
        const int row = wm + mi * 16 + lq * 4 + r;
        const float wgt = tok_w[e * NTOK + mt * TM + row];
        prow[(size_t)row * DDIM + col] = wgt * (acc[mi][ni][r] + bb3);
      }
    }
  }
}

// ---------------- Gather: y[tok] = pout[slot0] + pout[slot1] ----------------
__global__ __launch_bounds__(256) void gather_kernel(
    const float* __restrict__ pout, const int* __restrict__ tok_slot,
    const int* __restrict__ counts, float* __restrict__ y)
{
  const int tok = blockIdx.x;
  const int c = threadIdx.x;
  int off[NEXP];
  {
    int o = 0;
#pragma unroll
    for (int i = 0; i < NEXP; ++i) { off[i] = o; o += ((counts[i] + TM - 1) / TM) * TM; }
  }
  const int es0 = tok_slot[tok * 2 + 0];
  const int es1 = tok_slot[tok * 2 + 1];
  const size_t p0 = (size_t)(off[es0 >> 12] + (es0 & 4095));
  const size_t p1 = (size_t)(off[es1 >> 12] + (es1 & 4095));
  const f32x4 a = ((const f32x4*)pout)[p0 * 256 + c];
  const f32x4 b = ((const f32x4*)pout)[p1 * 256 + c];
  ((f32x4*)y)[(size_t)tok * 256 + c] = a + b;
}

// ================= SLOW fallback path (previous verified kernels) =================
__global__ __launch_bounds__(256, 2) void stagea_kernel(
    const float* __restrict__ x,
    const float* __restrict__ w1, const float* __restrict__ b1,
    const float* __restrict__ w2, const float* __restrict__ b2,
    const int* __restrict__ tok_id,
    const int* __restrict__ counts, const int* __restrict__ hoff,
    short* __restrict__ h)
{
  const int e = blockIdx.z;
  const int cnt = counts[e];
  const int mt = blockIdx.y;
  if (mt * TM >= cnt) return;
  const int nt = blockIdx.x;

  __shared__ __align__(16) short sA[TM * LDP];
  __shared__ __align__(16) short sB1[TN * LDP];
  __shared__ __align__(16) short sB2[TN * LDP];
  __shared__ int srow[TM];

  const int t = threadIdx.x;
  if (t < TM) {
    int id = tok_id[e * NTOK + mt * TM + t];
    srow[t] = id < 0 ? 0 : id;
  }

  const float* wa = w1 + (size_t)e * HDIM * DDIM + (size_t)(nt * TN) * DDIM;
  const float* wb = w2 + (size_t)e * HDIM * DDIM + (size_t)(nt * TN) * DDIM;

  const int lane = t & 63;
  const int wv = t >> 6;
  const int wm = (wv >> 1) * 64;
  const int wn = (wv & 1) * 64;
  const int lr = lane & 15;
  const int lq = lane >> 4;

  f32x4 acc1[4][4] = {};
  f32x4 acc2[4][4] = {};

  const int r0 = t >> 4;
  const int c4 = t & 15;

  for (int k0 = 0; k0 < DDIM; k0 += BK) {
    __syncthreads();
#pragma unroll
    for (int j = 0; j < 8; ++j) {
      const int r = r0 + j * 16;
      const f32x4 v = *(const f32x4*)(x + (size_t)srow[r] * DDIM + k0 + c4 * 4);
      bf16x4 bv = { f2bf(v[0]), f2bf(v[1]), f2bf(v[2]), f2bf(v[3]) };
      *(bf16x4*)(sA + r * LDP + c4 * 4) = bv;
    }
#pragma unroll
    for (int j = 0; j < 8; ++j) {
      const int r = r0 + j * 16;
      const f32x4 v1 = *(const f32x4*)(wa + (size_t)r * DDIM + k0 + c4 * 4);
      bf16x4 b1v = { f2bf(v1[0]), f2bf(v1[1]), f2bf(v1[2]), f2bf(v1[3]) };
      *(bf16x4*)(sB1 + r * LDP + c4 * 4) = b1v;
      const f32x4 v2 = *(const f32x4*)(wb + (size_t)r * DDIM + k0 + c4 * 4);
      bf16x4 b2v = { f2bf(v2[0]), f2bf(v2[1]), f2bf(v2[2]), f2bf(v2[3]) };
      *(bf16x4*)(sB2 + r * LDP + c4 * 4) = b2v;
    }
    __syncthreads();
#pragma unroll
    for (int ks = 0; ks < BK; ks += 32) {
      bf16x8 af[4], bfa[4], bfb[4];
#pragma unroll
      for (int mi = 0; mi < 4; ++mi)
        af[mi] = *(const bf16x8*)(sA + (wm + mi * 16 + lr) * LDP + ks + lq * 8);
#pragma unroll
      for (int ni = 0; ni < 4; ++ni) {
        bfa[ni] = *(const bf16x8*)(sB1 + (wn + ni * 16 + lr) * LDP + ks + lq * 8);
        bfb[ni] = *(const bf16x8*)(sB2 + (wn + ni * 16 + lr) * LDP + ks + lq * 8);
      }
#pragma unroll
      for (int mi = 0; mi < 4; ++mi)
#pragma unroll
        for (int ni = 0; ni < 4; ++ni) {
          acc1[mi][ni] = __builtin_amdgcn_mfma_f32_16x16x32_bf16(af[mi], bfa[ni], acc1[mi][ni], 0, 0, 0);
          acc2[mi][ni] = __builtin_amdgcn_mfma_f32_16x16x32_bf16(af[mi], bfb[ni], acc2[mi][ni], 0, 0, 0);
        }
    }
  }

  const int hbase = hoff[e] + mt * TM;
#pragma unroll
  for (int ni = 0; ni < 4; ++ni) {
    const int col = nt * TN + wn + ni * 16 + lr;
    const float bb1 = b1[e * HDIM + col];
    const float bb2 = b2[e * HDIM + col];
#pragma unroll
    for (int mi = 0; mi < 4; ++mi) {
#pragma unroll
      for (int r = 0; r < 4; ++r) {
        const int row = wm + mi * 16 + lq * 4 + r;
        const float z1 = acc1[mi][ni][r] + bb1;
        const float z2 = acc2[mi][ni][r] + bb2;
        const float hv = (z1 / (1.f + expf(-z1))) * z2;
        h[(size_t)(hbase + row) * HDIM + col] = f2bf(hv);
      }
    }
  }
}

__global__ __launch_bounds__(256, 2) void stageb_kernel(
    const short* __restrict__ h,
    const float* __restrict__ w3, const float* __restrict__ b3,
    const int* __restrict__ tok_id, const float* __restrict__ tok_w,
    const int* __restrict__ counts, const int* __restrict__ hoff,
    float* __restrict__ y)
{
  const int e = blockIdx.z;
  const int cnt = counts[e];
  const int mt = blockIdx.y;
  if (mt * TM >= cnt) return;
  const int nt = blockIdx.x;

  __shared__ __align__(16) short sA[TM * LDP];
  __shared__ __align__(16) short sB[TN * LDP];

  const int t = threadIdx.x;
  const int lane = t & 63;
  const int wv = t >> 6;
  const int wm = (wv >> 1) * 64;
  const int wn = (wv & 1) * 64;
  const int lr = lane & 15;
  const int lq = lane >> 4;

  const short* hrow = h + (size_t)(hoff[e] + mt * TM) * HDIM;
  const float* wc = w3 + (size_t)e * DDIM * HDIM + (size_t)(nt * TN) * HDIM;

  f32x4 acc[4][4] = {};

  const int rA = t >> 3;
  const int c8 = t & 7;
  const int rB = t >> 4;
  const int c4 = t & 15;

  for (int k0 = 0; k0 < HDIM; k0 += BK) {
    __syncthreads();
#pragma unroll
    for (int j = 0; j < 4; ++j) {
      const int r = rA + j * 32;
      bf16x8 v = *(const bf16x8*)(hrow + (size_t)r * HDIM + k0 + c8 * 8);
      *(bf16x8*)(sA + r * LDP + c8 * 8) = v;
    }
#pragma unroll
    for (int j = 0; j < 8; ++j) {
      const int r = rB + j * 16;
      const f32x4 v = *(const f32x4*)(wc + (size_t)r * HDIM + k0 + c4 * 4);
      bf16x4 bv = { f2bf(v[0]), f2bf(v[1]), f2bf(v[2]), f2bf(v[3]) };
      *(bf16x4*)(sB + r * LDP + c4 * 4) = bv;
    }
    __syncthreads();
#pragma unroll
    for (int ks = 0; ks < BK; ks += 32) {
      bf16x8 af[4], bfr[4];
#pragma unroll
      for (int mi = 0; mi < 4; ++mi)
        af[mi] = *(const bf16x8*)(sA + (wm + mi * 16 + lr) * LDP + ks + lq * 8);
#pragma unroll
      for (int ni = 0; ni < 4; ++ni)
        bfr[ni] = *(const bf16x8*)(sB + (wn + ni * 16 + lr) * LDP + ks + lq * 8);
#pragma unroll
      for (int mi = 0; mi < 4; ++mi)
#pragma unroll
        for (int ni = 0; ni < 4; ++ni)
          acc[mi][ni] = __builtin_amdgcn_mfma_f32_16x16x32_bf16(af[mi], bfr[ni], acc[mi][ni], 0, 0, 0);
    }
  }

#pragma unroll
  for (int ni = 0; ni < 4; ++ni) {
    const int col = nt * TN + wn + ni * 16 + lr;
    const float bb3 = b3[e * DDIM + col];
#pragma unroll
    for (int mi = 0; mi < 4; ++mi) {
#pragma unroll
      for (int r = 0; r < 4; ++r) {
        const int row = mt * TM + wm + mi * 16 + lq * 4 + r;
        const int tok = tok_id[e * NTOK + row];
        if (tok >= 0) {
          const float wgt = tok_w[e * NTOK + row];
          atomicAdd(&y[(size_t)tok * DDIM + col], wgt * (acc[mi][ni][r] + bb3));
        }
      }
    }
  }
}

extern "C" void kernel_launch(void* const* d_in, const int* in_sizes, int n_in,
                              void* d_out, int out_size, void* d_ws, size_t ws_size,
                              hipStream_t stream) {
  const float* x  = (const float*)d_in[0];
  const float* gw = (const float*)d_in[1];
  const float* rs = (const float*)d_in[2];
  const float* w1 = (const float*)d_in[3];
  const float* b1 = (const float*)d_in[4];
  const float* w2 = (const float*)d_in[5];
  const float* b2 = (const float*)d_in[6];
  const float* w3 = (const float*)d_in[7];
  const float* b3 = (const float*)d_in[8];
  // d_in[9] = top_k (fixed 2)

  char* ws = (char*)d_ws;
  int*   tok_id   = (int*)ws;                 // E*N ints      = 131072 B
  float* tok_w    = (float*)(ws + 131072);    // E*N floats    = 131072 B
  int*   counts   = (int*)(ws + 262144);      // 8 ints
  int*   hoff     = (int*)(ws + 262176);      // 8 ints (slow path only)
  int*   tok_slot = (int*)(ws + 262208);      // N*2 ints      = 32768 B  (ends 294976)

  // fast path: xb (8.39 MB) | h (75.5 MB) | w1b (67.1 MB) | w2b (67.1 MB)
  // stage B reuses w1b for w3b and w2b for pout (37.75 MB fp32 compact partials)
  const size_t OFF_XB = 295168;
  const size_t OFF_H  = OFF_XB + 8388608ull;           // 4096*1024*2
  const size_t OFF_WB = OFF_H  + 75497472ull;          // 9216*4096*2
  const size_t FAST_REQ = OFF_WB + 134217728ull;       // = 218,398,976 B
  const bool fast = ws_size >= FAST_REQ;

  hipMemsetAsync(counts, 0, 32, stream);
  hipMemsetAsync(tok_id, 0xFF, 131072, stream);   // pad token id = -1

  if (fast) {
    short* xb   = (short*)(ws + OFF_XB);
    short* h    = (short*)(ws + OFF_H);
    short* w1b  = (short*)(ws + OFF_WB);
    short* w2b  = w1b + 33554432;                 // 8*4096*1024 bf16
    float* pout = (float*)(ws + OFF_WB + 67108864ull);  // aliases w2b slot (dead after A)
    const int W4 = 8388608;                       // f32x4 count per weight tensor

    router_kernel<<<dim3(NTOK / 4), dim3(256), 0, stream>>>(x, gw, rs, tok_id, tok_w, counts, xb, tok_slot);
    convert2_kernel<<<dim3(2048, 1, 2), dim3(256), 0, stream>>>(w1, w1b, w2, w2b, W4);
    stagea_fast<<<dim3(HDIM / TN, NTOK / TM, NEXP), dim3(256), 0, stream>>>(
        xb, w1b, w2b, b1, b2, tok_id, counts, h);
    // w3 -> bf16 reuses the w1b slot (stage A done with it; stream-ordered)
    convert_kernel<<<dim3(2048), dim3(256), 0, stream>>>(w3, w1b, W4);
    stageb_fast<<<dim3(DDIM / TN, NTOK / TM, NEXP), dim3(256), 0, stream>>>(
        h, w1b, b3, tok_w, counts, pout);
    gather_kernel<<<dim3(NTOK), dim3(256), 0, stream>>>(pout, tok_slot, counts, (float*)d_out);
  } else {
    short* h = (short*)(ws + OFF_XB);
    hipMemsetAsync(d_out, 0, (size_t)out_size * sizeof(float), stream);
    router_kernel<<<dim3(NTOK / 4), dim3(256), 0, stream>>>(x, gw, rs, tok_id, tok_w, counts, (short*)nullptr, tok_slot);
    finalize_kernel<<<dim3(1), dim3(64), 0, stream>>>(counts, hoff);
    stagea_kernel<<<dim3(HDIM / TN, NTOK / TM, NEXP), dim3(256), 0, stream>>>(
        x, w1, b1, w2, b2, tok_id, counts, hoff, h);
    stageb_kernel<<<dim3(DDIM / TN, NTOK / TM, NEXP), dim3(256), 0, stream>>>(
        h, w3, b3, tok_id, tok_w, counts, hoff, (float*)d_out);
  }
}

// Round 6
// 749.559 us; speedup vs baseline: 1.7773x; 1.0938x over previous
//
#include <hip/hip_runtime.h>
#include <hip/hip_bf16.h>

#define NTOK 4096
#define DDIM 1024
#define HDIM 4096
#define NEXP 8
#define TM 128
#define TN 128
#define BK 64
#define LDP 72   // padded LDS row (slow fallback path only)

typedef __attribute__((ext_vector_type(4))) float f32x4;
typedef __attribute__((ext_vector_type(8))) short bf16x8;
typedef __attribute__((ext_vector_type(4))) short bf16x4;
typedef __attribute__((ext_vector_type(4))) int i32x4;

static __device__ __forceinline__ short f2bf(float f) {
  union { __hip_bfloat16 b; short s; } u;
  u.b = __float2bfloat16(f);
  return u.s;
}
static __device__ __forceinline__ float bits2f(int i) {
  union { int i; float f; } u; u.i = i; return u.f;
}
static __device__ __forceinline__ int f2bits(float f) {
  union { float f; int i; } u; u.f = f; return u.i;
}

// async global->LDS, 16B per lane. LDS dest is wave-uniform base + lane*16;
// global source is per-lane (gather / pre-swizzle OK).
static __device__ __forceinline__ void gl16(const void* g, void* l) {
  __builtin_amdgcn_global_load_lds((const __attribute__((address_space(1))) void*)g,
                                   (__attribute__((address_space(3))) void*)l, 16, 0, 0);
}

// ---------------- Router pass 1: logits + top-2 per token, NO atomics ----------------
// One wave per token; writes meta = (e0, e1, bits(w0), bits(w1)) and bf16 copy of x.
__global__ __launch_bounds__(256) void rlogits_kernel(
    const float* __restrict__ x, const float* __restrict__ gw,
    const float* __restrict__ rs,
    short* __restrict__ xb, i32x4* __restrict__ meta)
{
  const int wv = threadIdx.x >> 6;
  const int lane = threadIdx.x & 63;
  const int tok = blockIdx.x * 4 + wv;
  const f32x4* xr = (const f32x4*)(x + (size_t)tok * DDIM);
  f32x4 xv[4];
#pragma unroll
  for (int j = 0; j < 4; ++j) xv[j] = xr[j * 64 + lane];
#pragma unroll
  for (int j = 0; j < 4; ++j) {
    bf16x4 bv = { f2bf(xv[j][0]), f2bf(xv[j][1]), f2bf(xv[j][2]), f2bf(xv[j][3]) };
    *(bf16x4*)(xb + (size_t)tok * DDIM + (size_t)(j * 64 + lane) * 4) = bv;
  }
  float lg[NEXP];
#pragma unroll
  for (int e = 0; e < NEXP; ++e) {
    const f32x4* gr = (const f32x4*)(gw + (size_t)e * DDIM);
    float s = 0.f;
#pragma unroll
    for (int j = 0; j < 4; ++j) {
      f32x4 g = gr[j * 64 + lane];
      s += g[0]*xv[j][0] + g[1]*xv[j][1] + g[2]*xv[j][2] + g[3]*xv[j][3];
    }
#pragma unroll
    for (int off = 32; off > 0; off >>= 1) s += __shfl_down(s, off, 64);
    lg[e] = s;
  }
  if (lane == 0) {
    const float scale = rs[0];
#pragma unroll
    for (int e = 0; e < NEXP; ++e) lg[e] *= scale;
    int i0 = 0;
#pragma unroll
    for (int e = 1; e < NEXP; ++e) if (lg[e] > lg[i0]) i0 = e;   // first-occurrence max
    int i1 = (i0 == 0) ? 1 : 0;
#pragma unroll
    for (int e = 0; e < NEXP; ++e) if (e != i0 && lg[e] > lg[i1]) i1 = e;
    const float w0 = 1.f / (1.f + expf(lg[i1] - lg[i0]));   // softmax over the 2 picked
    i32x4 m = { i0, i1, f2bits(w0), f2bits(1.f - w0) };
    meta[tok] = m;
  }
}

// ---------------- Router pass 2: histogram + prefix + slot assignment, NO atomics ---------
// One block, 256 threads x 16 tokens. Deterministic (token-order slots per expert).
__global__ __launch_bounds__(256) void rassign_kernel(
    const i32x4* __restrict__ meta,
    int* __restrict__ tok_id, float* __restrict__ tok_w,
    int* __restrict__ counts, int* __restrict__ tok_slot)
{
  __shared__ int sh[256][NEXP];   // per-thread per-expert hist -> prefix base
  const int t = threadIdx.x;
  i32x4 m[16];
  int hist[NEXP];
#pragma unroll
  for (int e = 0; e < NEXP; ++e) hist[e] = 0;
#pragma unroll
  for (int k = 0; k < 16; ++k) {
    m[k] = meta[t * 16 + k];
#pragma unroll
    for (int e = 0; e < NEXP; ++e) {    // static-indexed increment (no dyn reg array)
      hist[e] += (m[k][0] == e) + (m[k][1] == e);
    }
  }
#pragma unroll
  for (int e = 0; e < NEXP; ++e) sh[t][e] = hist[e];
  __syncthreads();
  if (t < NEXP) {   // serial prefix over 256 thread-histograms for expert t
    int run = 0;
    for (int i = 0; i < 256; ++i) { int c = sh[i][t]; sh[i][t] = run; run += c; }
    counts[t] = run;   // plain store; only writer
  }
  __syncthreads();
#pragma unroll
  for (int k = 0; k < 16; ++k) {
    const int tok = t * 16 + k;
    const int e0 = m[k][0], e1 = m[k][1];
    int s0 = sh[t][e0]; sh[t][e0] = s0 + 1;    // thread owns its LDS row: race-free
    int s1 = sh[t][e1]; sh[t][e1] = s1 + 1;
    tok_id[e0 * NTOK + s0] = tok;  tok_w[e0 * NTOK + s0] = bits2f(m[k][2]);
    tok_id[e1 * NTOK + s1] = tok;  tok_w[e1 * NTOK + s1] = bits2f(m[k][3]);
    tok_slot[tok * 2 + 0] = (e0 << 12) | s0;
    tok_slot[tok * 2 + 1] = (e1 << 12) | s1;
  }
}

// ---------------- Router (slow fallback path, with atomics) ----------------
__global__ __launch_bounds__(256) void router_kernel(
    const float* __restrict__ x, const float* __restrict__ gw,
    const float* __restrict__ rs,
    int* __restrict__ tok_id, float* __restrict__ tok_w,
    int* __restrict__ counts)
{
  const int wv = threadIdx.x >> 6;
  const int lane = threadIdx.x & 63;
  const int tok = blockIdx.x * 4 + wv;
  const f32x4* xr = (const f32x4*)(x + (size_t)tok * DDIM);
  f32x4 xv[4];
#pragma unroll
  for (int j = 0; j < 4; ++j) xv[j] = xr[j * 64 + lane];
  float lg[NEXP];
#pragma unroll
  for (int e = 0; e < NEXP; ++e) {
    const f32x4* gr = (const f32x4*)(gw + (size_t)e * DDIM);
    float s = 0.f;
#pragma unroll
    for (int j = 0; j < 4; ++j) {
      f32x4 g = gr[j * 64 + lane];
      s += g[0]*xv[j][0] + g[1]*xv[j][1] + g[2]*xv[j][2] + g[3]*xv[j][3];
    }
#pragma unroll
    for (int off = 32; off > 0; off >>= 1) s += __shfl_down(s, off, 64);
    lg[e] = s;
  }
  if (lane == 0) {
    const float scale = rs[0];
#pragma unroll
    for (int e = 0; e < NEXP; ++e) lg[e] *= scale;
    int i0 = 0;
#pragma unroll
    for (int e = 1; e < NEXP; ++e) if (lg[e] > lg[i0]) i0 = e;
    int i1 = (i0 == 0) ? 1 : 0;
#pragma unroll
    for (int e = 0; e < NEXP; ++e) if (e != i0 && lg[e] > lg[i1]) i1 = e;
    const float w0 = 1.f / (1.f + expf(lg[i1] - lg[i0]));
    int s0 = atomicAdd(&counts[i0], 1);
    tok_id[i0 * NTOK + s0] = tok;  tok_w[i0 * NTOK + s0] = w0;
    int s1 = atomicAdd(&counts[i1], 1);
    tok_id[i1 * NTOK + s1] = tok;  tok_w[i1 * NTOK + s1] = 1.f - w0;
  }
}

// ---------------- Finalize (slow fallback only): padded prefix offsets ----------------
__global__ void finalize_kernel(const int* __restrict__ counts, int* __restrict__ hoff) {
  if (threadIdx.x == 0) {
    int off = 0;
    for (int e = 0; e < NEXP; ++e) { hoff[e] = off; off += ((counts[e] + TM - 1) / TM) * TM; }
  }
}

// padded prefix offset for expert e, computed in-register from counts (kills a dispatch)
static __device__ __forceinline__ int hoff_of(const int* __restrict__ counts, int e) {
  int off = 0;
#pragma unroll
  for (int i = 0; i < NEXP; ++i)
    if (i < e) off += ((counts[i] + TM - 1) / TM) * TM;
  return off;
}

// ---------------- fp32 -> bf16 streaming convert, up to 3 tensors via grid.z ----------
// 16B stores (bf16x8) for full write coalescing.
__global__ __launch_bounds__(256) void convert3_kernel(
    const float* __restrict__ s0, short* __restrict__ d0,
    const float* __restrict__ s1, short* __restrict__ d1,
    const float* __restrict__ s2, short* __restrict__ d2, int n8)
{
  const float* src; short* dst;
  if (blockIdx.z == 0)      { src = s0; dst = d0; }
  else if (blockIdx.z == 1) { src = s1; dst = d1; }
  else                      { src = s2; dst = d2; }
  int i = blockIdx.x * 256 + threadIdx.x;
  const int stride = gridDim.x * 256;
  for (; i < n8; i += stride) {
    const f32x4 a = ((const f32x4*)src)[2 * i];
    const f32x4 b = ((const f32x4*)src)[2 * i + 1];
    bf16x8 o = { f2bf(a[0]), f2bf(a[1]), f2bf(a[2]), f2bf(a[3]),
                 f2bf(b[0]), f2bf(b[1]), f2bf(b[2]), f2bf(b[3]) };
    ((bf16x8*)dst)[i] = o;
  }
}

// ---------------- FAST Stage A: h = silu(Xb@w1b^T + b1) * (Xb@w2b^T + b2) ----------------
// m97 structure + T2 XOR-swizzle. Register floor ~236/wave -> (256,2) max; (256,3) spills
// the accumulators (round-3 post-mortem: WRITE_SIZE 70MB -> 1.4GB, 3x slower). Do not raise.
__global__ __launch_bounds__(256, 2) void stagea_fast(
    const short* __restrict__ xb,
    const short* __restrict__ w1b, const short* __restrict__ w2b,
    const float* __restrict__ b1, const float* __restrict__ b2,
    const int* __restrict__ tok_id,
    const int* __restrict__ counts,
    short* __restrict__ h)
{
  const int e = blockIdx.z;
  const int cnt = counts[e];
  const int mt = blockIdx.y;
  if (mt * TM >= cnt) return;
  const int nt = blockIdx.x;
  const int hb = hoff_of(counts, e);

  __shared__ __align__(16) short sA[TM * BK];
  __shared__ __align__(16) short sB1[TN * BK];
  __shared__ __align__(16) short sB2[TN * BK];
  __shared__ int srow[TM];

  const int t = threadIdx.x;
  const int lane = t & 63;
  const int wv = t >> 6;

  if (t < TM) {
    int id = tok_id[e * NTOK + mt * TM + t];
    srow[t] = id < 0 ? 0 : id;   // pad rows duplicate token 0; discarded downstream
  }
  __syncthreads();

  const int sub = lane >> 3;
  const int c8  = lane & 7;
  const int csw = (c8 ^ sub) * 8;          // pre-swizzled source chunk (T2, rule 21)
  const short* wbase1 = w1b + (size_t)e * HDIM * DDIM + (size_t)(nt * TN) * DDIM;
  const short* wbase2 = w2b + (size_t)e * HDIM * DDIM + (size_t)(nt * TN) * DDIM;
  const short* ap[4]; const short* bp1[4]; const short* bp2[4];
#pragma unroll
  for (int j = 0; j < 4; ++j) {
    const int r = wv * 32 + j * 8 + sub;
    ap[j]  = xb + (size_t)srow[r] * DDIM + csw;
    bp1[j] = wbase1 + (size_t)r * DDIM + csw;
    bp2[j] = wbase2 + (size_t)r * DDIM + csw;
  }

  const int wm = (wv >> 1) * 64;
  const int wn = (wv & 1) * 64;
  const int lr = lane & 15;
  const int lq = lane >> 4;
  const int r7 = lr & 7;
  const int sw0 = ((lq ^ r7) << 3);
  const int sw1 = (((4 + lq) ^ r7) << 3);

  f32x4 acc1[4][4] = {};
  f32x4 acc2[4][4] = {};

  for (int k0 = 0; k0 < DDIM; k0 += BK) {
#pragma unroll
    for (int j = 0; j < 4; ++j) {
      gl16(ap[j] + k0,  sA  + (wv * 4 + j) * 512);
      gl16(bp1[j] + k0, sB1 + (wv * 4 + j) * 512);
      gl16(bp2[j] + k0, sB2 + (wv * 4 + j) * 512);
    }
    __syncthreads();
#pragma unroll
    for (int ks = 0; ks < 2; ++ks) {
      const int sw = ks ? sw1 : sw0;
      bf16x8 af[4], ba[4], bb[4];
#pragma unroll
      for (int mi = 0; mi < 4; ++mi)
        af[mi] = *(const bf16x8*)(sA + (wm + mi * 16 + lr) * BK + sw);
#pragma unroll
      for (int ni = 0; ni < 4; ++ni) {
        ba[ni] = *(const bf16x8*)(sB1 + (wn + ni * 16 + lr) * BK + sw);
        bb[ni] = *(const bf16x8*)(sB2 + (wn + ni * 16 + lr) * BK + sw);
      }
#pragma unroll
      for (int mi = 0; mi < 4; ++mi)
#pragma unroll
        for (int ni = 0; ni < 4; ++ni) {
          acc1[mi][ni] = __builtin_amdgcn_mfma_f32_16x16x32_bf16(af[mi], ba[ni], acc1[mi][ni], 0, 0, 0);
          acc2[mi][ni] = __builtin_amdgcn_mfma_f32_16x16x32_bf16(af[mi], bb[ni], acc2[mi][ni], 0, 0, 0);
        }
    }
    __syncthreads();
  }

  const int hbase = hb + mt * TM;
#pragma unroll
  for (int ni = 0; ni < 4; ++ni) {
    const int col = nt * TN + wn + ni * 16 + lr;
    const float bb1 = b1[e * HDIM + col];
    const float bb2 = b2[e * HDIM + col];
#pragma unroll
    for (int mi = 0; mi < 4; ++mi) {
#pragma unroll
      for (int r = 0; r < 4; ++r) {
        const int row = wm + mi * 16 + lq * 4 + r;
        const float z1 = acc1[mi][ni][r] + bb1;
        const float z2 = acc2[mi][ni][r] + bb2;
        const float hv = (z1 / (1.f + expf(-z1))) * z2;
        h[(size_t)(hbase + row) * HDIM + col] = f2bf(hv);
      }
    }
  }
}

// ---------------- FAST Stage B: pout[slot] = wgt * (h @ w3b^T + b3)  (atomic-free) --------
// (256,2): known-good config (register floor ~160/wave is marginal for 3 waves/EU).
__global__ __launch_bounds__(256, 2) void stageb_fast(
    const short* __restrict__ hm, const short* __restrict__ w3b,
    const float* __restrict__ b3, const float* __restrict__ tok_w,
    const int* __restrict__ counts,
    float* __restrict__ pout)
{
  const int e = blockIdx.z;
  const int cnt = counts[e];
  const int mt = blockIdx.y;
  if (mt * TM >= cnt) return;
  const int nt = blockIdx.x;
  const int hb = hoff_of(counts, e);

  __shared__ __align__(16) short sA[TM * BK];
  __shared__ __align__(16) short sB[TN * BK];

  const int t = threadIdx.x;
  const int lane = t & 63;
  const int wv = t >> 6;
  const int sub = lane >> 3;
  const int c8  = lane & 7;
  const int csw = (c8 ^ sub) * 8;

  const short* hrow = hm + (size_t)(hb + mt * TM) * HDIM;
  const short* wbase = w3b + (size_t)e * DDIM * HDIM + (size_t)(nt * TN) * HDIM;
  const short* ap[4]; const short* bp[4];
#pragma unroll
  for (int j = 0; j < 4; ++j) {
    const int r = wv * 32 + j * 8 + sub;
    ap[j] = hrow + (size_t)r * HDIM + csw;
    bp[j] = wbase + (size_t)r * HDIM + csw;
  }

  const int wm = (wv >> 1) * 64;
  const int wn = (wv & 1) * 64;
  const int lr = lane & 15;
  const int lq = lane >> 4;
  const int r7 = lr & 7;
  const int sw0 = ((lq ^ r7) << 3);
  const int sw1 = (((4 + lq) ^ r7) << 3);

  f32x4 acc[4][4] = {};

  for (int k0 = 0; k0 < HDIM; k0 += BK) {
#pragma unroll
    for (int j = 0; j < 4; ++j) {
      gl16(ap[j] + k0, sA + (wv * 4 + j) * 512);
      gl16(bp[j] + k0, sB + (wv * 4 + j) * 512);
    }
    __syncthreads();
#pragma unroll
    for (int ks = 0; ks < 2; ++ks) {
      const int sw = ks ? sw1 : sw0;
      bf16x8 af[4], bfr[4];
#pragma unroll
      for (int mi = 0; mi < 4; ++mi)
        af[mi] = *(const bf16x8*)(sA + (wm + mi * 16 + lr) * BK + sw);
#pragma unroll
      for (int ni = 0; ni < 4; ++ni)
        bfr[ni] = *(const bf16x8*)(sB + (wn + ni * 16 + lr) * BK + sw);
#pragma unroll
      for (int mi = 0; mi < 4; ++mi)
#pragma unroll
        for (int ni = 0; ni < 4; ++ni)
          acc[mi][ni] = __builtin_amdgcn_mfma_f32_16x16x32_bf16(af[mi], bfr[ni], acc[mi][ni], 0, 0, 0);
    }
    __syncthreads();
  }

  float* prow = pout + (size_t)(hb + mt * TM) * DDIM;
#pragma unroll
  for (int ni = 0; ni < 4; ++ni) {
    const int col = nt * TN + wn + ni * 16 + lr;
    const float bb3 = b3[e * DDIM + col];
#pragma unroll
    for (int mi = 0; mi < 4; ++mi) {
#pragma unroll
      for (int r = 0; r < 4; ++r) {
        const int row = wm + mi * 16 + lq * 4 + r;
        const float wgt = tok_w[e * NTOK + mt * TM + row];
        prow[(size_t)row * DDIM + col] = wgt * (acc[mi][ni][r] + bb3);
      }
    }
  }
}

// ---------------- Gather: y[tok] = pout[slot0] + pout[slot1] ----------------
__global__ __launch_bounds__(256) void gather_kernel(
    const float* __restrict__ pout, const int* __restrict__ tok_slot,
    const int* __restrict__ counts, float* __restrict__ y)
{
  const int tok = blockIdx.x;
  const int c = threadIdx.x;
  int off[NEXP];
  {
    int o = 0;
#pragma unroll
    for (int i = 0; i < NEXP; ++i) { off[i] = o; o += ((counts[i] + TM - 1) / TM) * TM; }
  }
  const int es0 = tok_slot[tok * 2 + 0];
  const int es1 = tok_slot[tok * 2 + 1];
  const size_t p0 = (size_t)(off[es0 >> 12] + (es0 & 4095));
  const size_t p1 = (size_t)(off[es1 >> 12] + (es1 & 4095));
  const f32x4 a = ((const f32x4*)pout)[p0 * 256 + c];
  const f32x4 b = ((const f32x4*)pout)[p1 * 256 + c];
  ((f32x4*)y)[(size_t)tok * 256 + c] = a + b;
}

// ================= SLOW fallback path (original verified kernels) =================
__global__ __launch_bounds__(256, 2) void stagea_kernel(
    const float* __restrict__ x,
    const float* __restrict__ w1, const float* __restrict__ b1,
    const float* __restrict__ w2, const float* __restrict__ b2,
    const int* __restrict__ tok_id,
    const int* __restrict__ counts, const int* __restrict__ hoff,
    short* __restrict__ h)
{
  const int e = blockIdx.z;
  const int cnt = counts[e];
  const int mt = blockIdx.y;
  if (mt * TM >= cnt) return;
  const int nt = blockIdx.x;

  __shared__ __align__(16) short sA[TM * LDP];
  __shared__ __align__(16) short sB1[TN * LDP];
  __shared__ __align__(16) short sB2[TN * LDP];
  __shared__ int srow[TM];

  const int t = threadIdx.x;
  if (t < TM) {
    int id = tok_id[e * NTOK + mt * TM + t];
    srow[t] = id < 0 ? 0 : id;
  }

  const float* wa = w1 + (size_t)e * HDIM * DDIM + (size_t)(nt * TN) * DDIM;
  const float* wb = w2 + (size_t)e * HDIM * DDIM + (size_t)(nt * TN) * DDIM;

  const int lane = t & 63;
  const int wv = t >> 6;
  const int wm = (wv >> 1) * 64;
  const int wn = (wv & 1) * 64;
  const int lr = lane & 15;
  const int lq = lane >> 4;

  f32x4 acc1[4][4] = {};
  f32x4 acc2[4][4] = {};

  const int r0 = t >> 4;
  const int c4 = t & 15;

  for (int k0 = 0; k0 < DDIM; k0 += BK) {
    __syncthreads();
#pragma unroll
    for (int j = 0; j < 8; ++j) {
      const int r = r0 + j * 16;
      const f32x4 v = *(const f32x4*)(x + (size_t)srow[r] * DDIM + k0 + c4 * 4);
      bf16x4 bv = { f2bf(v[0]), f2bf(v[1]), f2bf(v[2]), f2bf(v[3]) };
      *(bf16x4*)(sA + r * LDP + c4 * 4) = bv;
    }
#pragma unroll
    for (int j = 0; j < 8; ++j) {
      const int r = r0 + j * 16;
      const f32x4 v1 = *(const f32x4*)(wa + (size_t)r * DDIM + k0 + c4 * 4);
      bf16x4 b1v = { f2bf(v1[0]), f2bf(v1[1]), f2bf(v1[2]), f2bf(v1[3]) };
      *(bf16x4*)(sB1 + r * LDP + c4 * 4) = b1v;
      const f32x4 v2 = *(const f32x4*)(wb + (size_t)r * DDIM + k0 + c4 * 4);
      bf16x4 b2v = { f2bf(v2[0]), f2bf(v2[1]), f2bf(v2[2]), f2bf(v2[3]) };
      *(bf16x4*)(sB2 + r * LDP + c4 * 4) = b2v;
    }
    __syncthreads();
#pragma unroll
    for (int ks = 0; ks < BK; ks += 32) {
      bf16x8 af[4], bfa[4], bfb[4];
#pragma unroll
      for (int mi = 0; mi < 4; ++mi)
        af[mi] = *(const bf16x8*)(sA + (wm + mi * 16 + lr) * LDP + ks + lq * 8);
#pragma unroll
      for (int ni = 0; ni < 4; ++ni) {
        bfa[ni] = *(const bf16x8*)(sB1 + (wn + ni * 16 + lr) * LDP + ks + lq * 8);
        bfb[ni] = *(const bf16x8*)(sB2 + (wn + ni * 16 + lr) * LDP + ks + lq * 8);
      }
#pragma unroll
      for (int mi = 0; mi < 4; ++mi)
#pragma unroll
        for (int ni = 0; ni < 4; ++ni) {
          acc1[mi][ni] = __builtin_amdgcn_mfma_f32_16x16x32_bf16(af[mi], bfa[ni], acc1[mi][ni], 0, 0, 0);
          acc2[mi][ni] = __builtin_amdgcn_mfma_f32_16x16x32_bf16(af[mi], bfb[ni], acc2[mi][ni], 0, 0, 0);
        }
    }
  }

  const int hbase = hoff[e] + mt * TM;
#pragma unroll
  for (int ni = 0; ni < 4; ++ni) {
    const int col = nt * TN + wn + ni * 16 + lr;
    const float bb1 = b1[e * HDIM + col];
    const float bb2 = b2[e * HDIM + col];
#pragma unroll
    for (int mi = 0; mi < 4; ++mi) {
#pragma unroll
      for (int r = 0; r < 4; ++r) {
        const int row = wm + mi * 16 + lq * 4 + r;
        const float z1 = acc1[mi][ni][r] + bb1;
        const float z2 = acc2[mi][ni][r] + bb2;
        const float hv = (z1 / (1.f + expf(-z1))) * z2;
        h[(size_t)(hbase + row) * HDIM + col] = f2bf(hv);
      }
    }
  }
}

__global__ __launch_bounds__(256, 2) void stageb_kernel(
    const short* __restrict__ h,
    const float* __restrict__ w3, const float* __restrict__ b3,
    const int* __restrict__ tok_id, const float* __restrict__ tok_w,
    const int* __restrict__ counts, const int* __restrict__ hoff,
    float* __restrict__ y)
{
  const int e = blockIdx.z;
  const int cnt = counts[e];
  const int mt = blockIdx.y;
  if (mt * TM >= cnt) return;
  const int nt = blockIdx.x;

  __shared__ __align__(16) short sA[TM * LDP];
  __shared__ __align__(16) short sB[TN * LDP];

  const int t = threadIdx.x;
  const int lane = t & 63;
  const int wv = t >> 6;
  const int wm = (wv >> 1) * 64;
  const int wn = (wv & 1) * 64;
  const int lr = lane & 15;
  const int lq = lane >> 4;

  const short* hrow = h + (size_t)(hoff[e] + mt * TM) * HDIM;
  const float* wc = w3 + (size_t)e * DDIM * HDIM + (size_t)(nt * TN) * HDIM;

  f32x4 acc[4][4] = {};

  const int rA = t >> 3;
  const int c8 = t & 7;
  const int rB = t >> 4;
  const int c4 = t & 15;

  for (int k0 = 0; k0 < HDIM; k0 += BK) {
    __syncthreads();
#pragma unroll
    for (int j = 0; j < 4; ++j) {
      const int r = rA + j * 32;
      bf16x8 v = *(const bf16x8*)(hrow + (size_t)r * HDIM + k0 + c8 * 8);
      *(bf16x8*)(sA + r * LDP + c8 * 8) = v;
    }
#pragma unroll
    for (int j = 0; j < 8; ++j) {
      const int r = rB + j * 16;
      const f32x4 v = *(const f32x4*)(wc + (size_t)r * HDIM + k0 + c4 * 4);
      bf16x4 bv = { f2bf(v[0]), f2bf(v[1]), f2bf(v[2]), f2bf(v[3]) };
      *(bf16x4*)(sB + r * LDP + c4 * 4) = bv;
    }
    __syncthreads();
#pragma unroll
    for (int ks = 0; ks < BK; ks += 32) {
      bf16x8 af[4], bfr[4];
#pragma unroll
      for (int mi = 0; mi < 4; ++mi)
        af[mi] = *(const bf16x8*)(sA + (wm + mi * 16 + lr) * LDP + ks + lq * 8);
#pragma unroll
      for (int ni = 0; ni < 4; ++ni)
        bfr[ni] = *(const bf16x8*)(sB + (wn + ni * 16 + lr) * LDP + ks + lq * 8);
#pragma unroll
      for (int mi = 0; mi < 4; ++mi)
#pragma unroll
        for (int ni = 0; ni < 4; ++ni)
          acc[mi][ni] = __builtin_amdgcn_mfma_f32_16x16x32_bf16(af[mi], bfr[ni], acc[mi][ni], 0, 0, 0);
    }
  }

#pragma unroll
  for (int ni = 0; ni < 4; ++ni) {
    const int col = nt * TN + wn + ni * 16 + lr;
    const float bb3 = b3[e * DDIM + col];
#pragma unroll
    for (int mi = 0; mi < 4; ++mi) {
#pragma unroll
      for (int r = 0; r < 4; ++r) {
        const int row = mt * TM + wm + mi * 16 + lq * 4 + r;
        const int tok = tok_id[e * NTOK + row];
        if (tok >= 0) {
          const float wgt = tok_w[e * NTOK + row];
          atomicAdd(&y[(size_t)tok * DDIM + col], wgt * (acc[mi][ni][r] + bb3));
        }
      }
    }
  }
}

extern "C" void kernel_launch(void* const* d_in, const int* in_sizes, int n_in,
                              void* d_out, int out_size, void* d_ws, size_t ws_size,
                              hipStream_t stream) {
  const float* x  = (const float*)d_in[0];
  const float* gw = (const float*)d_in[1];
  const float* rs = (const float*)d_in[2];
  const float* w1 = (const float*)d_in[3];
  const float* b1 = (const float*)d_in[4];
  const float* w2 = (const float*)d_in[5];
  const float* b2 = (const float*)d_in[6];
  const float* w3 = (const float*)d_in[7];
  const float* b3 = (const float*)d_in[8];
  // d_in[9] = top_k (fixed 2)

  char* ws = (char*)d_ws;
  int*   tok_id   = (int*)ws;                 // E*N ints      = 131072 B
  float* tok_w    = (float*)(ws + 131072);    // E*N floats    = 131072 B
  int*   counts   = (int*)(ws + 262144);      // 8 ints
  int*   hoff     = (int*)(ws + 262176);      // 8 ints (slow path only)
  int*   tok_slot = (int*)(ws + 262208);      // N*2 ints      = 32768 B  (ends 294976)
  i32x4* meta     = (i32x4*)(ws + 294976);    // N*16 B        = 65536 B  (ends 360512)

  // fast layouts (bytes):
  //   common: xb (8.39 MB) | h (75.5 MB) | w1b (67.1 MB) | w2b (67.1 MB)
  //   FAST3 adds: w3b (67.1 MB); pout (37.75 MB) aliases w1b (dead after stage A)
  //   FAST2: pout aliases w2b; w3b aliases w1b (converted between stages)
  const size_t OFF_XB = 360576;
  const size_t OFF_H  = OFF_XB + 8388608ull;            // 4096*1024*2
  const size_t OFF_WB = OFF_H  + 75497472ull;           // 9216*4096*2
  const size_t FAST2_REQ = OFF_WB + 134217728ull;       // w1b+w2b
  const size_t FAST3_REQ = OFF_WB + 201326592ull;       // w1b+w2b+w3b
  const bool fast3 = ws_size >= FAST3_REQ;
  const bool fast2 = ws_size >= FAST2_REQ;

  hipMemsetAsync(counts, 0, 32, stream);
  hipMemsetAsync(tok_id, 0xFF, 131072, stream);   // pad token id = -1

  const int W8 = 4194304;   // bf16x8 count per weight tensor

  if (fast3) {
    short* xb   = (short*)(ws + OFF_XB);
    short* h    = (short*)(ws + OFF_H);
    short* w1b  = (short*)(ws + OFF_WB);
    short* w2b  = w1b + 33554432;
    short* w3b  = w2b + 33554432;
    float* pout = (float*)w1b;   // alias w1b: dead after stage A

    rlogits_kernel<<<dim3(NTOK / 4), dim3(256), 0, stream>>>(x, gw, rs, xb, meta);
    rassign_kernel<<<dim3(1), dim3(256), 0, stream>>>(meta, tok_id, tok_w, counts, tok_slot);
    convert3_kernel<<<dim3(2048, 1, 3), dim3(256), 0, stream>>>(w1, w1b, w2, w2b, w3, w3b, W8);
    stagea_fast<<<dim3(HDIM / TN, NTOK / TM, NEXP), dim3(256), 0, stream>>>(
        xb, w1b, w2b, b1, b2, tok_id, counts, h);
    stageb_fast<<<dim3(DDIM / TN, NTOK / TM, NEXP), dim3(256), 0, stream>>>(
        h, w3b, b3, tok_w, counts, pout);
    gather_kernel<<<dim3(NTOK), dim3(256), 0, stream>>>(pout, tok_slot, counts, (float*)d_out);
  } else if (fast2) {
    short* xb   = (short*)(ws + OFF_XB);
    short* h    = (short*)(ws + OFF_H);
    short* w1b  = (short*)(ws + OFF_WB);
    short* w2b  = w1b + 33554432;
    float* pout = (float*)w2b;   // alias w2b: dead after stage A

    rlogits_kernel<<<dim3(NTOK / 4), dim3(256), 0, stream>>>(x, gw, rs, xb, meta);
    rassign_kernel<<<dim3(1), dim3(256), 0, stream>>>(meta, tok_id, tok_w, counts, tok_slot);
    convert3_kernel<<<dim3(2048, 1, 2), dim3(256), 0, stream>>>(w1, w1b, w2, w2b, w1, w1b, W8);
    stagea_fast<<<dim3(HDIM / TN, NTOK / TM, NEXP), dim3(256), 0, stream>>>(
        xb, w1b, w2b, b1, b2, tok_id, counts, h);
    convert3_kernel<<<dim3(2048, 1, 1), dim3(256), 0, stream>>>(w3, w1b, w3, w1b, w3, w1b, W8);
    stageb_fast<<<dim3(DDIM / TN, NTOK / TM, NEXP), dim3(256), 0, stream>>>(
        h, w1b, b3, tok_w, counts, pout);
    gather_kernel<<<dim3(NTOK), dim3(256), 0, stream>>>(pout, tok_slot, counts, (float*)d_out);
  } else {
    short* h = (short*)(ws + OFF_XB);
    hipMemsetAsync(d_out, 0, (size_t)out_size * sizeof(float), stream);
    router_kernel<<<dim3(NTOK / 4), dim3(256), 0, stream>>>(x, gw, rs, tok_id, tok_w, counts);
    finalize_kernel<<<dim3(1), dim3(64), 0, stream>>>(counts, hoff);
    stagea_kernel<<<dim3(HDIM / TN, NTOK / TM, NEXP), dim3(256), 0, stream>>>(
        x, w1, b1, w2, b2, tok_id, counts, hoff, h);
    stageb_kernel<<<dim3(DDIM / TN, NTOK / TM, NEXP), dim3(256), 0, stream>>>(
        h, w3, b3, tok_id, tok_w, counts, hoff, (float*)d_out);
  }
}